// Round 17
// baseline (567.538 us; speedup 1.0000x reference)
//
#include <hip/hip_runtime.h>
#include <hip/hip_cooperative_groups.h>

namespace cg = cooperative_groups;

constexpr int IN_F  = 128;
constexpr int OUT_F = 64;
constexpr int NB_BLOCKS = 256;   // edge-chunk count for hist/scatter phases
constexpr int BIN_SHIFT = 6;     // 64 nodes per bin
constexpr int MAX_BINS  = 1024;  // N <= 65536
constexpr int BIN_CAP   = 4096;  // per-bin LDS sort capacity (mean 1023, sd 32 -> huge margin)

using bf16x8 = __attribute__((ext_vector_type(8))) short;
using f32x4  = __attribute__((ext_vector_type(4))) float;

__device__ inline short f2bf(float f) {  // RNE float->bf16
    unsigned u = __builtin_bit_cast(unsigned, f);
    u += 0x7fffu + ((u >> 16) & 1u);
    return (short)(u >> 16);
}
__device__ inline float bf2f(unsigned short u) {
    unsigned x = ((unsigned)u) << 16;
    return __builtin_bit_cast(float, x);
}

// ================= fused build: gemm + hist + colscan + binscan + scatter + binsort =================
// grid = nbins (782) blocks x 256 threads, cooperative. LDS phases share a union (17.4 KB).
// __launch_bounds__(256,4): 4 waves/EU -> <=128 VGPR -> 4 blocks/CU -> 1024 co-resident >= 782.
__global__ __launch_bounds__(256, 4) void build_kernel(
        const float* __restrict__ feats, const float* __restrict__ weight,
        unsigned short* __restrict__ h,
        const int* __restrict__ src, const int* __restrict__ dst,
        int* __restrict__ histmat, int* __restrict__ tot,
        int* __restrict__ binbase, int* __restrict__ offs,
        unsigned int* __restrict__ bucket,
        int N, int E, int nbins) {
    cg::grid_group grid = cg::this_grid();

    __shared__ union {
        short wbT[OUT_F][IN_F + 8];                                  // P0: 17408 B
        int   hl[MAX_BINS];                                          // P1
        int   s[NB_BLOCKS];                                          // P2
        struct { int vals[MAX_BINS]; int part[256]; } bs;            // P3
        int   cur[MAX_BINS];                                         // P4
        struct { unsigned buf[BIN_CAP]; int cnt[64]; int off[64]; } srt;  // P5: 16896 B
    } sh;

    const int t    = threadIdx.x;
    const int lane = t & 63;

    // ---------- P0: GEMM tile (all 782 blocks; 782*64 >= N) ----------
    {
        for (int idx = t; idx < IN_F * OUT_F; idx += 256)
            sh.wbT[idx & 63][idx >> 6] = f2bf(weight[idx]);  // coalesced read, transpose write
        __syncthreads();

        const int wid   = t >> 6;
        const int kg    = lane >> 4;
        const int node0 = blockIdx.x * 64 + wid * 16;
        const int an    = min(node0 + (lane & 15), N - 1);   // clamp; invalid rows not stored
        const float* ap = feats + (size_t)an * IN_F;

        f32x4 acc[4] = {{0,0,0,0},{0,0,0,0},{0,0,0,0},{0,0,0,0}};
        #pragma unroll
        for (int ks = 0; ks < 4; ++ks) {
            const int kbase = ks * 32 + kg * 8;
            const float4 a0 = *reinterpret_cast<const float4*>(ap + kbase);
            const float4 a1 = *reinterpret_cast<const float4*>(ap + kbase + 4);
            bf16x8 a;
            a[0] = f2bf(a0.x); a[1] = f2bf(a0.y); a[2] = f2bf(a0.z); a[3] = f2bf(a0.w);
            a[4] = f2bf(a1.x); a[5] = f2bf(a1.y); a[6] = f2bf(a1.z); a[7] = f2bf(a1.w);
            #pragma unroll
            for (int nt = 0; nt < 4; ++nt) {
                const bf16x8 b = *reinterpret_cast<const bf16x8*>(&sh.wbT[nt * 16 + (lane & 15)][kbase]);
                acc[nt] = __builtin_amdgcn_mfma_f32_16x16x32_bf16(a, b, acc[nt], 0, 0, 0);
            }
        }
        #pragma unroll
        for (int nt = 0; nt < 4; ++nt)
            #pragma unroll
            for (int r = 0; r < 4; ++r) {
                const int n = node0 + (lane >> 4) * 4 + r;
                if (n < N) h[(size_t)n * OUT_F + nt * 16 + (lane & 15)] = (unsigned short)f2bf(acc[nt][r]);
            }
    }
    grid.sync();

    // ---------- P1: per-chunk histogram over bins (blocks 0..255) ----------
    if (blockIdx.x < NB_BLOCKS) {
        for (int i = t; i < nbins; i += 256) sh.hl[i] = 0;
        __syncthreads();
        const int chunk = (E + NB_BLOCKS - 1) / NB_BLOCKS;
        const int beg = blockIdx.x * chunk, end = min(E, beg + chunk);
        for (int e = beg + t; e < end; e += 256)
            atomicAdd(&sh.hl[dst[e] >> BIN_SHIFT], 1);
        __syncthreads();
        for (int i = t; i < nbins; i += 256)
            histmat[blockIdx.x * nbins + i] = sh.hl[i];
    }
    grid.sync();

    // ---------- P2: per-bin exclusive scan over the 256 chunks (all blocks) ----------
    {
        const int b = blockIdx.x;
        const int v = histmat[t * nbins + b];
        sh.s[t] = v;
        __syncthreads();
        for (int off = 1; off < NB_BLOCKS; off <<= 1) {
            const int u = (t >= off) ? sh.s[t - off] : 0;
            __syncthreads();
            sh.s[t] += u;
            __syncthreads();
        }
        histmat[t * nbins + b] = sh.s[t] - v;   // exclusive over chunks
        if (t == NB_BLOCKS - 1) tot[b] = sh.s[t];
    }
    grid.sync();

    // ---------- P3: exclusive scan of bin totals (block 0) ----------
    if (blockIdx.x == 0) {
        for (int i = t; i < MAX_BINS; i += 256) sh.bs.vals[i] = (i < nbins) ? tot[i] : 0;
        __syncthreads();
        int ssum = 0;
        #pragma unroll
        for (int j = 0; j < 4; ++j) ssum += sh.bs.vals[t * 4 + j];
        sh.bs.part[t] = ssum;
        __syncthreads();
        for (int off = 1; off < 256; off <<= 1) {
            const int u = (t >= off) ? sh.bs.part[t - off] : 0;
            __syncthreads();
            sh.bs.part[t] += u;
            __syncthreads();
        }
        int run = sh.bs.part[t] - ssum;   // exclusive base of this thread's 4-segment
        #pragma unroll
        for (int j = 0; j < 4; ++j) {
            const int i = t * 4 + j;
            if (i < nbins) binbase[i] = run;
            run += sh.bs.vals[i];
        }
        if (t == 0) binbase[nbins] = E;
    }
    grid.sync();

    // ---------- P4: deterministic scatter into bins, LDS cursors (blocks 0..255) ----------
    if (blockIdx.x < NB_BLOCKS) {
        for (int i = t; i < nbins; i += 256)
            sh.cur[i] = binbase[i] + histmat[blockIdx.x * nbins + i];
        __syncthreads();
        const int chunk = (E + NB_BLOCKS - 1) / NB_BLOCKS;
        const int beg = blockIdx.x * chunk, end = min(E, beg + chunk);
        for (int e = beg + t; e < end; e += 256) {
            const int d = dst[e];
            const int pos = atomicAdd(&sh.cur[d >> BIN_SHIFT], 1);
            bucket[pos] = ((unsigned)(d & 63) << 16) | (unsigned)src[e];  // src < 65536
        }
    }
    grid.sync();

    // ---------- P5: per-bin counting sort (in place) -> per-node CSR offs (all blocks) ----------
    {
        const int b    = blockIdx.x;
        const int base = binbase[b];
        const int cnt  = min(binbase[b + 1] - base, BIN_CAP);  // clamp (never triggers at this E)

        for (int i = t; i < cnt; i += 256) sh.srt.buf[i] = bucket[base + i];
        if (t < 64) sh.srt.cnt[t] = 0;
        __syncthreads();
        for (int i = t; i < cnt; i += 256)
            atomicAdd(&sh.srt.cnt[sh.srt.buf[i] >> 16], 1);
        __syncthreads();

        int v = 0;
        if (t < 64) { v = sh.srt.cnt[t]; sh.srt.off[t] = v; }
        __syncthreads();
        for (int off = 1; off < 64; off <<= 1) {
            int u = 0;
            if (t >= off && t < 64) u = sh.srt.off[t - off];
            __syncthreads();
            if (t < 64) sh.srt.off[t] += u;
            __syncthreads();
        }
        if (t < 64) {
            const int excl = sh.srt.off[t] - v;
            const int node = (b << BIN_SHIFT) + t;
            if (node < N) offs[node] = base + excl;
            sh.srt.off[t] = excl;   // becomes the scatter cursor
        }
        __syncthreads();

        for (int i = t; i < cnt; i += 256) {
            const unsigned wdv = sh.srt.buf[i];
            const int pos = atomicAdd(&sh.srt.off[wdv >> 16], 1);
            bucket[base + pos] = wdv;
        }
        if (b == nbins - 1 && t == 0) offs[N] = E;
    }
}

// ================= gather: pull-mode CSR (bf16 h) + bias + ReLU =================
__global__ __launch_bounds__(256) void gather_kernel(
        const unsigned short* __restrict__ h, const unsigned int* __restrict__ bucket,
        const int* __restrict__ offs, const float* __restrict__ bias,
        float* __restrict__ out, int N) {
    const int lane   = threadIdx.x & 63;
    const int gwave  = (blockIdx.x * blockDim.x + threadIdx.x) >> 6;
    const int nwaves = (gridDim.x * blockDim.x) >> 6;
    const float b = bias[lane];
    for (int n = gwave; n < N; n += nwaves) {
        const int beg = offs[n], end = offs[n + 1];
        float acc = 0.f;
        int i = beg;
        for (; i + 8 <= end; i += 8) {
            const unsigned w0 = bucket[i + 0], w1 = bucket[i + 1];
            const unsigned w2 = bucket[i + 2], w3 = bucket[i + 3];
            const unsigned w4 = bucket[i + 4], w5 = bucket[i + 5];
            const unsigned w6 = bucket[i + 6], w7 = bucket[i + 7];
            const unsigned short u0 = h[(size_t)(w0 & 0xffffu) * OUT_F + lane];
            const unsigned short u1 = h[(size_t)(w1 & 0xffffu) * OUT_F + lane];
            const unsigned short u2 = h[(size_t)(w2 & 0xffffu) * OUT_F + lane];
            const unsigned short u3 = h[(size_t)(w3 & 0xffffu) * OUT_F + lane];
            const unsigned short u4 = h[(size_t)(w4 & 0xffffu) * OUT_F + lane];
            const unsigned short u5 = h[(size_t)(w5 & 0xffffu) * OUT_F + lane];
            const unsigned short u6 = h[(size_t)(w6 & 0xffffu) * OUT_F + lane];
            const unsigned short u7 = h[(size_t)(w7 & 0xffffu) * OUT_F + lane];
            acc += bf2f(u0); acc += bf2f(u1); acc += bf2f(u2); acc += bf2f(u3);
            acc += bf2f(u4); acc += bf2f(u5); acc += bf2f(u6); acc += bf2f(u7);
        }
        for (; i < end; ++i)
            acc += bf2f(h[(size_t)(bucket[i] & 0xffffu) * OUT_F + lane]);
        out[(size_t)n * OUT_F + lane] = fmaxf(acc + b, 0.f);
    }
}

extern "C" void kernel_launch(void* const* d_in, const int* in_sizes, int n_in,
                              void* d_out, int out_size, void* d_ws, size_t ws_size,
                              hipStream_t stream) {
    const float* feats  = (const float*)d_in[0];
    const float* weight = (const float*)d_in[1];
    const float* bias   = (const float*)d_in[2];
    const int*   src    = (const int*)d_in[3];
    const int*   dst    = (const int*)d_in[4];
    float* out = (float*)d_out;

    int N = in_sizes[0] / IN_F;
    int E = in_sizes[3];
    int nbins = (N + 63) >> BIN_SHIFT;  // 782 for N=50000

    // workspace layout (~11 MB)
    unsigned short* h = (unsigned short*)d_ws;              // N*64 bf16
    unsigned* bucket  = (unsigned*)(h + (size_t)N * OUT_F); // E words
    int*      histmat = (int*)(bucket + E);                 // NB_BLOCKS * nbins
    int*      tot     = histmat + NB_BLOCKS * nbins;        // nbins
    int*      binbase = tot + nbins;                        // nbins + 1
    int*      offs    = binbase + nbins + 1;                // N + 1

    void* args[] = { (void*)&feats, (void*)&weight, (void*)&h, (void*)&src, (void*)&dst,
                     (void*)&histmat, (void*)&tot, (void*)&binbase, (void*)&offs,
                     (void*)&bucket, (void*)&N, (void*)&E, (void*)&nbins };
    hipLaunchCooperativeKernel((const void*)build_kernel, dim3(nbins), dim3(256),
                               args, 0, stream);
    // 2048 x 256 = 8192 waves = full residency; writes every out row (no memset needed)
    gather_kernel<<<2048, 256, 0, stream>>>(h, bucket, offs, bias, out, N);
}